// Round 9
// baseline (460.248 us; speedup 1.0000x reference)
//
#include <hip/hip_runtime.h>
#include <math.h>

// Problem constants
constexpr int E = 8, H = 1024, DFF = 2048, T = 4096;
constexpr int TR = 8192;          // total routed rows = T * topk
constexpr int MAXJ = 72;          // max (expert, m-tile) jobs: 8192/128 + E
constexpr int NT2 = 16;           // k2 n-tiles per job (DFF/128)
constexpr int NT3 = 8;            // k3 n-tiles per job (H/128)
constexpr int PERS_BLOCKS = 768;  // 256 CU x 3 blocks/CU (48 KB LDS)

typedef __bf16 bf16x8 __attribute__((ext_vector_type(8)));
typedef __bf16 bf16x4 __attribute__((ext_vector_type(4)));
typedef float f32x4 __attribute__((ext_vector_type(4)));

__device__ __forceinline__ void gload16(const void* g, void* l) {
    __builtin_amdgcn_global_load_lds(
        (const __attribute__((address_space(1))) unsigned int*)g,
        (__attribute__((address_space(3))) unsigned int*)l, 16, 0, 0);
}

// ================= shared GEMM task bodies (single source of truth) =================

// k2 task: gate+up dual GEMM for (jt, nt). PROVEN body (94 us kernel, rounds 0/2/6).
__device__ __forceinline__ void k2_task(
    __bf16* As, __bf16* Bg, __bf16* Bu,
    const __bf16* __restrict__ xb, const __bf16* __restrict__ gwb,
    const __bf16* __restrict__ uwb, const int* __restrict__ cnt,
    const int* __restrict__ off, const int* __restrict__ token_list,
    const int* __restrict__ jobs, __bf16* __restrict__ h, int jt, int nt) {
    int job = jobs[jt];
    int e = job >> 6, mt = job & 63;
    int Me = cnt[e], offe = off[e];

    int tid = threadIdx.x;
    int lane = tid & 63, w = tid >> 6;
    int wm = w >> 1, wn = w & 1;

    const __bf16* asrc[4];
    const __bf16 *bsg[4], *bsu[4];
    #pragma unroll
    for (int rr = 0; rr < 4; rr++) {
        int l = rr * 256 + tid;
        int row = l >> 3, sl = l & 7;
        int gr = mt * 128 + row; if (gr >= Me) gr = Me - 1;
        int tok = token_list[e * T + gr];
        asrc[rr] = xb + (size_t)tok * H + ((sl ^ (row & 7)) * 8);
        size_t base = ((size_t)e * DFF + nt * 128 + row) * H + ((sl ^ (row & 7)) * 8);
        bsg[rr] = gwb + base;
        bsu[rr] = uwb + base;
    }

    f32x4 accg[4][4] = {};
    f32x4 accu[4][4] = {};
    int kq = lane >> 4, m15 = lane & 15;

    for (int k0 = 0; k0 < H; k0 += 64) {
        #pragma unroll
        for (int rr = 0; rr < 4; rr++) {
            gload16(asrc[rr] + k0, &As[(rr * 256 + tid) * 8]);
            gload16(bsg[rr] + k0, &Bg[(rr * 256 + tid) * 8]);
            gload16(bsu[rr] + k0, &Bu[(rr * 256 + tid) * 8]);
        }
        __syncthreads();

        #pragma unroll
        for (int kc = 0; kc < 2; kc++) {
            bf16x8 af[4], gf[4], uf[4];
            #pragma unroll
            for (int i = 0; i < 4; i++) {
                int row = wm * 64 + i * 16 + m15;
                int sl = (kc * 4 + kq) ^ (row & 7);
                af[i] = *(const bf16x8*)&As[row * 64 + sl * 8];
            }
            #pragma unroll
            for (int j = 0; j < 4; j++) {
                int row = wn * 64 + j * 16 + m15;
                int sl = (kc * 4 + kq) ^ (row & 7);
                gf[j] = *(const bf16x8*)&Bg[row * 64 + sl * 8];
                uf[j] = *(const bf16x8*)&Bu[row * 64 + sl * 8];
            }
            #pragma unroll
            for (int i = 0; i < 4; i++)
                #pragma unroll
                for (int j = 0; j < 4; j++) {
                    accg[i][j] = __builtin_amdgcn_mfma_f32_16x16x32_bf16(af[i], gf[j], accg[i][j], 0, 0, 0);
                    accu[i][j] = __builtin_amdgcn_mfma_f32_16x16x32_bf16(af[i], uf[j], accu[i][j], 0, 0, 0);
                }
        }
        __syncthreads();
    }

    // epilogue: h = silu(g) * u
    #pragma unroll
    for (int i = 0; i < 4; i++)
        #pragma unroll
        for (int j = 0; j < 4; j++) {
            int nloc = wn * 64 + j * 16 + m15;
            size_t c = (size_t)nt * 128 + nloc;
            #pragma unroll
            for (int p = 0; p < 4; p++) {
                int mloc = wm * 64 + i * 16 + kq * 4 + p;
                int mrow = mt * 128 + mloc;
                if (mrow < Me) {
                    float g = accg[i][j][p], u = accu[i][j][p];
                    float sig = 1.0f / (1.0f + __expf(-g));
                    h[(size_t)(offe + mrow) * DFF + c] = (__bf16)(g * sig * u);
                }
            }
        }
}

// k3 task: down GEMM for (jt, nt) + fused weighted atomic combine into out.
__device__ __forceinline__ void k3_task(
    __bf16* As, __bf16* Bs,
    const __bf16* __restrict__ h, const __bf16* __restrict__ dwb,
    const int* __restrict__ cnt, const int* __restrict__ off,
    const int* __restrict__ token_list, const float* __restrict__ wlist,
    const int* __restrict__ jobs, float* __restrict__ out, int jt, int nt) {
    int job = jobs[jt];
    int e = job >> 6, mt = job & 63;
    int Me = cnt[e], offe = off[e];

    int tid = threadIdx.x;
    int lane = tid & 63, w = tid >> 6;
    int wm = w >> 1, wn = w & 1;

    const __bf16* asrc[4];
    const __bf16* bsrc[4];
    #pragma unroll
    for (int rr = 0; rr < 4; rr++) {
        int l = rr * 256 + tid;
        int row = l >> 3, sl = l & 7;
        int koff = (sl ^ (row & 7)) * 8;
        int gr = mt * 128 + row; if (gr >= Me) gr = Me - 1;
        asrc[rr] = h + (size_t)(offe + gr) * DFF + koff;
        bsrc[rr] = dwb + ((size_t)e * H + nt * 128 + row) * DFF + koff;
    }

    f32x4 acc[4][4] = {};
    int kq = lane >> 4, m15 = lane & 15;

    for (int k0 = 0; k0 < DFF; k0 += 64) {
        #pragma unroll
        for (int rr = 0; rr < 4; rr++)
            gload16(asrc[rr] + k0, &As[(rr * 256 + tid) * 8]);
        #pragma unroll
        for (int rr = 0; rr < 4; rr++)
            gload16(bsrc[rr] + k0, &Bs[(rr * 256 + tid) * 8]);
        __syncthreads();

        #pragma unroll
        for (int kc = 0; kc < 2; kc++) {
            bf16x8 af[4], bf[4];
            #pragma unroll
            for (int i = 0; i < 4; i++) {
                int row = wm * 64 + i * 16 + m15;
                int sl = (kc * 4 + kq) ^ (row & 7);
                af[i] = *(const bf16x8*)&As[row * 64 + sl * 8];
            }
            #pragma unroll
            for (int j = 0; j < 4; j++) {
                int row = wn * 64 + j * 16 + m15;
                int sl = (kc * 4 + kq) ^ (row & 7);
                bf[j] = *(const bf16x8*)&Bs[row * 64 + sl * 8];
            }
            #pragma unroll
            for (int i = 0; i < 4; i++)
                #pragma unroll
                for (int j = 0; j < 4; j++)
                    acc[i][j] = __builtin_amdgcn_mfma_f32_16x16x32_bf16(af[i], bf[j], acc[i][j], 0, 0, 0);
        }
        __syncthreads();
    }

    // fused epilogue: out[tok] += w * acc (2 commutative f32 adds per element)
    #pragma unroll
    for (int i = 0; i < 4; i++) {
        #pragma unroll
        for (int p = 0; p < 4; p++) {
            int mloc = wm * 64 + i * 16 + kq * 4 + p;
            int mrow = mt * 128 + mloc;
            if (mrow < Me) {
                int tok = token_list[e * T + mrow];
                float wgt = wlist[e * T + mrow];
                float* orow = out + (size_t)tok * H;
                #pragma unroll
                for (int j = 0; j < 4; j++) {
                    int nglob = nt * 128 + wn * 64 + j * 16 + m15;
                    atomicAdd(&orow[nglob], wgt * acc[i][j][p]);
                }
            }
        }
    }
}

// ---------------- k0: fused conversions (gw,uw[,dw],x -> bf16) + out-zero + affinity ----------------
constexpr int CONV_BLOCKS = 3072;
__global__ __launch_bounds__(256) void k0_fused(
    const float* __restrict__ x, const float* __restrict__ cent,
    const float* __restrict__ bias,
    int* __restrict__ se, float* __restrict__ sw,
    const float* __restrict__ gw, __bf16* __restrict__ gwb,
    const float* __restrict__ uw, __bf16* __restrict__ uwb,
    const float* __restrict__ dw, __bf16* __restrict__ dwb,   // dw may be null (smallws)
    __bf16* __restrict__ xb, float* __restrict__ outz,
    int w4, int x4, int o4, int* __restrict__ ctrl) {
    __shared__ float cs[E * H];
    int tid = threadIdx.x;

    // ctrl[0]=done, ctrl[1]=ticket, ctrl[2..73]=rg[72] — re-zero every replay
    if (blockIdx.x == 0 && tid < 74) ctrl[tid] = 0;

    if (blockIdx.x >= 1024) {
        int nw = (dw != nullptr) ? 3 : 2;
        int total = nw * w4 + x4 + o4;
        int stride = CONV_BLOCKS * 256;
        for (int i = (blockIdx.x - 1024) * 256 + tid; i < total; i += stride) {
            if (i >= nw * w4 + x4) {
                float4 z = {0.f, 0.f, 0.f, 0.f};
                ((float4*)outz)[i - nw * w4 - x4] = z;
                continue;
            }
            const float* in; __bf16* outp; int idx;
            if (i < w4) { in = gw; outp = gwb; idx = i; }
            else if (i < 2 * w4) { in = uw; outp = uwb; idx = i - w4; }
            else if (nw == 3 && i < 3 * w4) { in = dw; outp = dwb; idx = i - 2 * w4; }
            else { in = x; outp = xb; idx = i - nw * w4; }
            float4 v = ((const float4*)in)[idx];
            bf16x4 o = {(__bf16)v.x, (__bf16)v.y, (__bf16)v.z, (__bf16)v.w};
            ((bf16x4*)outp)[idx] = o;
        }
        return;
    }

    // affinity role
    for (int i = tid; i < E * H / 4; i += 256)
        ((float4*)cs)[i] = ((const float4*)cent)[i];
    __syncthreads();

    int wave = tid >> 6, lane = tid & 63;
    int t = blockIdx.x * 4 + wave;
    const float4* xr = (const float4*)(x + (size_t)t * H);
    float acc[E] = {};
    #pragma unroll
    for (int it = 0; it < 4; it++) {
        float4 xv = xr[lane + it * 64];
        #pragma unroll
        for (int e = 0; e < E; e++) {
            float4 cv = ((const float4*)(cs + e * H))[lane + it * 64];
            acc[e] = fmaf(xv.x, cv.x, acc[e]);
            acc[e] = fmaf(xv.y, cv.y, acc[e]);
            acc[e] = fmaf(xv.z, cv.z, acc[e]);
            acc[e] = fmaf(xv.w, cv.w, acc[e]);
        }
    }
    #pragma unroll
    for (int off = 32; off; off >>= 1)
        #pragma unroll
        for (int e = 0; e < E; e++) acc[e] += __shfl_down(acc[e], off);

    if (lane == 0) {
        float s[E];
        #pragma unroll
        for (int e = 0; e < E; e++)
            s[e] = 1.0f / (1.0f + expf(-acc[e])) + bias[e];
        int i0 = 0;
        for (int e = 1; e < E; e++) if (s[e] > s[i0]) i0 = e;
        int i1 = -1;
        for (int e = 0; e < E; e++) {
            if (e == i0) continue;
            if (i1 < 0 || s[e] > s[i1]) i1 = e;
        }
        float m = fmaxf(s[i0], s[i1]);
        float w0 = expf(s[i0] - m), w1 = expf(s[i1] - m);
        float inv = 1.0f / (w0 + w1);
        se[2 * t] = i0;     sw[2 * t] = w0 * inv;
        se[2 * t + 1] = i1; sw[2 * t + 1] = w1 * inv;
    }
}

// ---------------- k1b: per-expert partition (+ weight) + (last block) offsets/jobs ----------------
__global__ __launch_bounds__(1024) void k1b_partition(
    const int* __restrict__ se, const float* __restrict__ sw,
    int* __restrict__ token_list, float* __restrict__ wlist,
    int* __restrict__ cnt,
    int* __restrict__ off, float* __restrict__ out_counts,
    int* __restrict__ jobs, int* __restrict__ njobs, int* __restrict__ ctrl) {
    int e = blockIdx.x;
    int tid = threadIdx.x;
    int wave = tid >> 6, lane = tid & 63;
    __shared__ int wsum[16];
    int running = 0;
    for (int c0 = 0; c0 < 2 * T; c0 += 1024) {
        int i = c0 + tid;
        bool pred = (se[i] == e);
        unsigned long long mask = __ballot(pred);
        int pos_in_wave = __popcll(mask & ((1ull << lane) - 1ull));
        if (lane == 0) wsum[wave] = __popcll(mask);
        __syncthreads();
        int wbase = 0;
        #pragma unroll
        for (int w2 = 0; w2 < 16; w2++) {
            int v = wsum[w2];
            if (w2 < wave) wbase += v;
        }
        int total = 0;
        #pragma unroll
        for (int w2 = 0; w2 < 16; w2++) total += wsum[w2];
        if (pred) {
            int p = running + wbase + pos_in_wave;
            token_list[e * T + p] = i >> 1;
            wlist[e * T + p] = sw[i];
        }
        running += total;
        __syncthreads();
    }
    if (tid == 0) {
        __hip_atomic_store(&cnt[e], running, __ATOMIC_RELEASE, __HIP_MEMORY_SCOPE_AGENT);
        int prev = __hip_atomic_fetch_add(&ctrl[0], 1, __ATOMIC_ACQ_REL, __HIP_MEMORY_SCOPE_AGENT);
        if (prev == E - 1) {
            int acc = 0, nj = 0;
            for (int e2 = 0; e2 < E; e2++) {
                int c = __hip_atomic_load(&cnt[e2], __ATOMIC_ACQUIRE, __HIP_MEMORY_SCOPE_AGENT);
                off[e2] = acc; acc += c;
                out_counts[e2] = (float)c;
                int mts = (c + 127) >> 7;
                for (int mt = 0; mt < mts; mt++) jobs[nj++] = e2 * 64 + mt;
            }
            njobs[0] = nj;
        }
    }
}

// ---------------- conv: fp32 -> bf16 (dw; smallws fallback only) ----------------
constexpr int KCONV_BLOCKS = 1024;
__global__ __launch_bounds__(256) void k_conv(const float* __restrict__ in,
                                              __bf16* __restrict__ out, int n4) {
    int stride = KCONV_BLOCKS * 256;
    for (int i = blockIdx.x * 256 + threadIdx.x; i < n4; i += stride) {
        float4 v = ((const float4*)in)[i];
        bf16x4 o = {(__bf16)v.x, (__bf16)v.y, (__bf16)v.z, (__bf16)v.w};
        ((bf16x4*)out)[i] = o;
    }
}

// ---------------- k23_fused: persistent task-queue (bigws path) ----------------
// Tickets [0, nj*16): k2 tasks; [nj*16, nj*24): k3 tasks (spin on rowgroup done).
// Deadlock-free: tickets claimed in order by running blocks; k3 spinners depend
// only on already-claimed k2 tasks.
__global__ __launch_bounds__(256, 2) void k23_fused(
    const __bf16* __restrict__ xb, const __bf16* __restrict__ gwb,
    const __bf16* __restrict__ uwb, const __bf16* __restrict__ dwb,
    const int* __restrict__ cnt, const int* __restrict__ off,
    const int* __restrict__ token_list, const float* __restrict__ wlist,
    const int* __restrict__ jobs, const int* __restrict__ njobs,
    __bf16* __restrict__ h, float* __restrict__ out, int* __restrict__ ctrl) {
    __shared__ __bf16 As[128 * 64];   // 16 KB
    __shared__ __bf16 B0[128 * 64];   // 16 KB (k2: gate; k3: down-weights)
    __shared__ __bf16 B1[128 * 64];   // 16 KB (k2: up; k3: unused)
    __shared__ int stick;

    int tid = threadIdx.x;
    int* ticket = &ctrl[1];
    int* rg = &ctrl[2];

    for (;;) {
        __syncthreads();   // LDS + stick reuse fence between tasks
        if (tid == 0)
            stick = __hip_atomic_fetch_add(ticket, 1, __ATOMIC_RELAXED, __HIP_MEMORY_SCOPE_AGENT);
        __syncthreads();
        int t = stick;
        int nj = njobs[0];
        int nk2 = nj * NT2, nk3 = nj * NT3;

        if (t < nk2) {
            int jt = t >> 4, nt = t & 15;
            k2_task(As, B0, B1, xb, gwb, uwb, cnt, off, token_list, jobs, h, jt, nt);
            __syncthreads();   // all threads' h-stores issued before the release
            if (tid == 0)
                __hip_atomic_fetch_add(&rg[jt], 1, __ATOMIC_RELEASE, __HIP_MEMORY_SCOPE_AGENT);
        } else if (t < nk2 + nk3) {
            int t3 = t - nk2;
            int jt = t3 >> 3, nt = t3 & 7;
            if (tid == 0) {
                while (__hip_atomic_load(&rg[jt], __ATOMIC_ACQUIRE, __HIP_MEMORY_SCOPE_AGENT) < NT2)
                    __builtin_amdgcn_s_sleep(8);
            }
            __syncthreads();
            k3_task(As, B0, h, dwb, cnt, off, token_list, wlist, jobs, out, jt, nt);
        } else {
            break;
        }
    }
}

// ---------------- standalone k2/k3 (smallws fallback; same task bodies) ----------------
__global__ __launch_bounds__(256, 2) void k2_gateup(
    const __bf16* __restrict__ xb, const __bf16* __restrict__ gwb,
    const __bf16* __restrict__ uwb, const int* __restrict__ cnt,
    const int* __restrict__ off, const int* __restrict__ token_list,
    const int* __restrict__ jobs, const int* __restrict__ njobs,
    __bf16* __restrict__ h) {
    int jt = blockIdx.x >> 4, nt = blockIdx.x & 15;
    if (jt >= njobs[0]) return;
    __shared__ __bf16 As[128 * 64];
    __shared__ __bf16 Bg[128 * 64];
    __shared__ __bf16 Bu[128 * 64];
    k2_task(As, Bg, Bu, xb, gwb, uwb, cnt, off, token_list, jobs, h, jt, nt);
}

__global__ __launch_bounds__(256, 2) void k3_down(
    const __bf16* __restrict__ h, const __bf16* __restrict__ dwb,
    const int* __restrict__ cnt, const int* __restrict__ off,
    const int* __restrict__ token_list, const float* __restrict__ wlist,
    const int* __restrict__ jobs, const int* __restrict__ njobs,
    float* __restrict__ out) {
    int jt = blockIdx.x >> 3, nt = blockIdx.x & 7;
    if (jt >= njobs[0]) return;
    __shared__ __bf16 As[128 * 64];
    __shared__ __bf16 Bs[128 * 64];
    k3_task(As, Bs, h, dwb, cnt, off, token_list, wlist, jobs, out, jt, nt);
}

// ---------------- launch ----------------
extern "C" void kernel_launch(void* const* d_in, const int* in_sizes, int n_in,
                              void* d_out, int out_size, void* d_ws, size_t ws_size,
                              hipStream_t stream) {
    const float* x    = (const float*)d_in[0];
    const float* cent = (const float*)d_in[1];
    const float* gw   = (const float*)d_in[2];
    const float* uw   = (const float*)d_in[3];
    const float* dw   = (const float*)d_in[4];
    const float* bias = (const float*)d_in[5];
    float* out = (float*)d_out;

    // control/workspace layout (bytes)
    char* ws = (char*)d_ws;
    int*   cnt        = (int*)(ws + 0);
    int*   off        = (int*)(ws + 64);
    int*   se         = (int*)(ws + 128);               // 32 KB
    float* sw         = (float*)(ws + 128 + 32768);     // 32 KB
    int*   token_list = (int*)(ws + 128 + 65536);       // 128 KB
    float* wlist      = (float*)(ws + 128 + 196608);    // 128 KB
    int*   jobs       = (int*)(ws + 327808);            // 80 ints
    int*   njobs      = (int*)(ws + 328128);            // 2 ints
    int*   ctrl       = (int*)(ws + 328192);            // done, ticket, rg[72]
    const size_t MB = 1u << 20;

    bool bigws = (ws_size >= 138 * MB);

    __bf16 *gwb, *uwb, *dwb, *xb, *h;
    if (bigws) {
        gwb = (__bf16*)(ws + 1 * MB);                   // 32 MB
        uwb = (__bf16*)(ws + 1 * MB + 33554432);        // 32 MB
        dwb = (__bf16*)(ws + 1 * MB + 67108864);        // 32 MB
        xb  = (__bf16*)(ws + 1 * MB + 100663296);       // 8 MB
        h   = (__bf16*)(ws + 1 * MB + 109051904);       // 32 MB (top = 137 MB)
    } else {
        gwb = (__bf16*)(ws + 1 * MB);                   // 32 MB
        uwb = (__bf16*)(ws + 1 * MB + 33554432);        // 32 MB
        dwb = gwb;                                      // alias: converted after k2
        xb  = (__bf16*)(ws + 1 * MB + 67108864);        // 8 MB
        h   = (__bf16*)(ws + 1 * MB + 75497472);        // 32 MB (top = 105 MB)
    }

    const int W4 = E * DFF * H / 4;
    const int X4 = T * H / 4;
    const int O4 = T * H / 4;

    k0_fused<<<1024 + CONV_BLOCKS, 256, 0, stream>>>(
        x, cent, bias, se, sw, gw, gwb, uw, uwb,
        bigws ? dw : nullptr, dwb, xb, out, W4, X4, O4, ctrl);
    k1b_partition<<<E, 1024, 0, stream>>>(se, sw, token_list, wlist, cnt,
                                          off, out + (size_t)T * H, jobs, njobs, ctrl);
    if (bigws) {
        k23_fused<<<PERS_BLOCKS, 256, 0, stream>>>(
            xb, gwb, uwb, dwb, cnt, off, token_list, wlist, jobs, njobs, h, out, ctrl);
    } else {
        k2_gateup<<<MAXJ * 16, 256, 0, stream>>>(xb, gwb, uwb, cnt, off, token_list, jobs, njobs, h);
        k_conv<<<KCONV_BLOCKS, 256, 0, stream>>>(dw, dwb, W4);
        k3_down<<<MAXJ * 8, 256, 0, stream>>>(h, dwb, cnt, off, token_list, wlist, jobs, njobs, out);
    }
}